// Round 4
// baseline (1909.589 us; speedup 1.0000x reference)
//
#include <hip/hip_runtime.h>
#include <hip/hip_bf16.h>
#include <stdint.h>

typedef __bf16 bf16;
typedef bf16 bf16x8 __attribute__((ext_vector_type(8)));
typedef float f32x4 __attribute__((ext_vector_type(4)));

#define MFMA_BF16(a, b, c) __builtin_amdgcn_mfma_f32_16x16x32_bf16((a), (b), (c), 0, 0, 0)

// problem constants
#define BB 8
#define LL 4160
#define DD 1024
#define HH 16
#define NTT 4096
#define NTOK (BB * LL)   // 33280
#define NSPLIT 13
#define KCHUNK 320       // 13*320 = 4160

__device__ __forceinline__ f32x4 zero4() {
  f32x4 z = {0.0f, 0.0f, 0.0f, 0.0f};
  return z;
}

// Flexible-dtype load of 8 contiguous elements (external inputs may be fp32
// or bf16; flag decided at runtime on-device). idx is in ELEMENTS.
__device__ __forceinline__ bf16x8 load8(const void* p, size_t idx, int f32) {
  if (f32) {
    const float* q = (const float*)p + idx;
    bf16x8 r;
#pragma unroll
    for (int j = 0; j < 8; ++j) r[j] = (bf16)q[j];
    return r;
  }
  return *(const bf16x8*)((const bf16*)p + idx);
}

__device__ __forceinline__ float loadS(const void* p, size_t idx, int f32) {
  return f32 ? ((const float*)p)[idx] : (float)((const bf16*)p)[idx];
}

// Flexible-dtype store of 8 contiguous elements from a bf16 source buffer.
__device__ __forceinline__ void storeOut8(void* out, size_t idx,
                                          const bf16* src, int f32) {
  if (f32) {
    float* o = (float*)out + idx;
#pragma unroll
    for (int j = 0; j < 8; ++j) o[j] = (float)src[j];
  } else {
    *(bf16x8*)((bf16*)out + idx) = *(const bf16x8*)src;
  }
}

// ---------------------------------------------------------------------------
// Dtype probe: bf16 N(0,1) data has biased-exponent in ~[116,130] and never
// hits 0x00/0xFF; fp32 data's low uint16s are ~uniform -> ~256/65536 hits.
// ---------------------------------------------------------------------------
__global__ __launch_bounds__(256) void detect_dtype(
    const unsigned short* __restrict__ q, int* __restrict__ flag) {
  __shared__ int cnt;
  if (threadIdx.x == 0) cnt = 0;
  __syncthreads();
  int c = 0;
  for (int i = threadIdx.x; i < 65536; i += 256) {
    const int e = (q[i] >> 7) & 0xFF;
    c += (e == 0 || e == 0xFF) ? 1 : 0;
  }
  atomicAdd(&cnt, c);
  __syncthreads();
  if (threadIdx.x == 0) *flag = (cnt > 64) ? 1 : 0;
}

// ---------------------------------------------------------------------------
// C[M,N] = A[M,K] @ W[N,K]^T + bias[N]   (flex in, bf16 out, fp32 accum)
// 128x128 tile, BK=32, 4 waves each computing 64x64 via 4x4 MFMA 16x16x32.
// ---------------------------------------------------------------------------
__global__ __launch_bounds__(256) void gemm_bt(
    const void* __restrict__ A, size_t a_off, const void* __restrict__ W,
    size_t w_off, const void* __restrict__ bias, int b_off,
    bf16* __restrict__ C, int M, int N, int K, int ntn,
    const int* __restrict__ dflag, int a_ext) {
  __shared__ __align__(16) bf16 As[128 * 32];
  __shared__ __align__(16) bf16 Bs[128 * 32];
  const int f = *dflag;
  const int af32 = a_ext ? f : 0;
  const int tid = threadIdx.x;
  const int wave = tid >> 6;
  const int lane = tid & 63;
  const int quad = lane >> 4;
  const int m16 = lane & 15;
  const int bid = blockIdx.x;
  const int row0 = (bid / ntn) * 128;
  const int col0 = (bid % ntn) * 128;
  const int wm = (wave >> 1) * 64;
  const int wn = (wave & 1) * 64;

  f32x4 acc[4][4];
#pragma unroll
  for (int i = 0; i < 4; ++i)
#pragma unroll
    for (int j = 0; j < 4; ++j) acc[i][j] = zero4();

  // staging: thread t covers rows sr and sr+64, cols sc..sc+7 of the 128x32 tile
  const int sr = tid >> 2;       // 0..63
  const int sc = (tid & 3) * 8;  // 0,8,16,24
  const size_t ai0 = a_off + (size_t)(row0 + sr) * K + sc;
  const size_t ai1 = a_off + (size_t)(row0 + sr + 64) * K + sc;
  const size_t wi0 = w_off + (size_t)(col0 + sr) * K + sc;
  const size_t wi1 = w_off + (size_t)(col0 + sr + 64) * K + sc;

  for (int kb = 0; kb < K; kb += 32) {
    const bf16x8 a0 = load8(A, ai0 + kb, af32);
    const bf16x8 a1 = load8(A, ai1 + kb, af32);
    const bf16x8 b0 = load8(W, wi0 + kb, f);
    const bf16x8 b1 = load8(W, wi1 + kb, f);
    __syncthreads();  // previous iteration's LDS readers done
    *(bf16x8*)&As[sr * 32 + sc] = a0;
    *(bf16x8*)&As[(sr + 64) * 32 + sc] = a1;
    *(bf16x8*)&Bs[sr * 32 + sc] = b0;
    *(bf16x8*)&Bs[(sr + 64) * 32 + sc] = b1;
    __syncthreads();
    bf16x8 af[4], bfv[4];
#pragma unroll
    for (int i = 0; i < 4; ++i)
      af[i] = *(const bf16x8*)&As[(wm + i * 16 + m16) * 32 + quad * 8];
#pragma unroll
    for (int j = 0; j < 4; ++j)
      bfv[j] = *(const bf16x8*)&Bs[(wn + j * 16 + m16) * 32 + quad * 8];
#pragma unroll
    for (int i = 0; i < 4; ++i)
#pragma unroll
      for (int j = 0; j < 4; ++j)
        acc[i][j] = MFMA_BF16(af[i], bfv[j], acc[i][j]);
  }

#pragma unroll
  for (int j = 0; j < 4; ++j) {
    const int col = col0 + wn + j * 16 + m16;
    const float bv = loadS(bias, b_off + col, f);
#pragma unroll
    for (int i = 0; i < 4; ++i) {
      const int row = row0 + wm + i * 16 + quad * 4;
#pragma unroll
      for (int r = 0; r < 4; ++r)
        C[(size_t)(row + r) * N + col] = (bf16)(acc[i][j][r] + bv);
    }
  }
}

// ---------------------------------------------------------------------------
// Temporal block attention: one wave per (b, nb, h). 64 q x 128 k x 64 dh.
// Q/K/V are ws (bf16); masks and Out are flex-dtype.
// ---------------------------------------------------------------------------
__global__ __launch_bounds__(64) void temporal_attn(
    const bf16* __restrict__ Q, const bf16* __restrict__ K,
    const bf16* __restrict__ V, const void* __restrict__ tmask,
    const void* __restrict__ smask, void* __restrict__ Out,
    const int* __restrict__ dflag) {
  __shared__ __align__(16) char smem[42496];
  bf16* Qs = (bf16*)smem;                 // [64][64]   8KB
  bf16* Ks = (bf16*)(smem + 8192);        // [128][64] 16KB
  bf16* Vt = (bf16*)(smem + 24576);       // [64][136] 17408B (dh-major, padded)
  float* biasS = (float*)(smem + 41984);  // [128]
  bf16* P = (bf16*)smem;                  // [64][136] aliases Qs+Ks
  bf16* Ost = (bf16*)smem;                // [64][64] aliases P after PV

  const int f = *dflag;
  const int bid = blockIdx.x;
  const int h = bid & 15;
  const int nb = (bid >> 4) & 63;
  const int b = bid >> 10;
  const int lane = threadIdx.x;
  const int quad = lane >> 4;
  const int m16 = lane & 15;

  const size_t tbase = ((size_t)b * LL + nb * 64) * DD + h * 64;
  const size_t sbase = ((size_t)b * LL + NTT) * DD + h * 64;

  {
    const int r = lane >> 3;
    const int cc = (lane & 7) * 8;
#pragma unroll
    for (int j = 0; j < 8; ++j) {
      const int rr = j * 8 + r;
      *(bf16x8*)&Qs[rr * 64 + cc] = *(const bf16x8*)&Q[tbase + (size_t)rr * DD + cc];
      *(bf16x8*)&Ks[rr * 64 + cc] = *(const bf16x8*)&K[tbase + (size_t)rr * DD + cc];
      *(bf16x8*)&Ks[(64 + rr) * 64 + cc] = *(const bf16x8*)&K[sbase + (size_t)rr * DD + cc];
    }
  }
  // V transposed into Vt[dh][k] (lane = dh column)
#pragma unroll
  for (int kb = 0; kb < 16; ++kb) {
    bf16x8 tmp;
#pragma unroll
    for (int j = 0; j < 8; ++j) {
      const int kk = kb * 8 + j;
      const size_t rowb = (kk < 64) ? (tbase + (size_t)kk * DD)
                                    : (sbase + (size_t)(kk - 64) * DD);
      tmp[j] = V[rowb + lane];
    }
    *(bf16x8*)&Vt[lane * 136 + kb * 8] = tmp;
  }
  {
    const float m1 = loadS(tmask, ((size_t)b * 64 + nb) * 64 + lane, f);
    const float m2 = loadS(smask, b * 64 + lane, f);
    biasS[lane] = (m1 > 0.5f) ? 0.0f : -1e30f;
    biasS[64 + lane] = (m2 > 0.5f) ? 0.0f : -1e30f;
  }
  __syncthreads();

  // S = Q @ K^T  (4 q-tiles x 8 k-tiles)
  f32x4 s[4][8];
#pragma unroll
  for (int i = 0; i < 4; ++i)
#pragma unroll
    for (int kt = 0; kt < 8; ++kt) s[i][kt] = zero4();

#pragma unroll
  for (int ks = 0; ks < 2; ++ks) {
    bf16x8 aq[4];
#pragma unroll
    for (int i = 0; i < 4; ++i)
      aq[i] = *(const bf16x8*)&Qs[(i * 16 + m16) * 64 + ks * 32 + quad * 8];
#pragma unroll
    for (int kt = 0; kt < 8; ++kt) {
      const bf16x8 bk = *(const bf16x8*)&Ks[(kt * 16 + m16) * 64 + ks * 32 + quad * 8];
#pragma unroll
      for (int i = 0; i < 4; ++i) s[i][kt] = MFMA_BF16(aq[i], bk, s[i][kt]);
    }
  }

  const float scale = 0.125f;
  float invl[4][4];
#pragma unroll
  for (int i = 0; i < 4; ++i)
#pragma unroll
    for (int r = 0; r < 4; ++r) {
      float mx = -1e30f;
#pragma unroll
      for (int kt = 0; kt < 8; ++kt) {
        float v = s[i][kt][r] * scale + biasS[kt * 16 + m16];
        s[i][kt][r] = v;
        mx = fmaxf(mx, v);
      }
#pragma unroll
      for (int off = 1; off < 16; off <<= 1) mx = fmaxf(mx, __shfl_xor(mx, off));
      float sum = 0.0f;
#pragma unroll
      for (int kt = 0; kt < 8; ++kt) {
        float p = __expf(s[i][kt][r] - mx);
        s[i][kt][r] = p;
        sum += p;
      }
#pragma unroll
      for (int off = 1; off < 16; off <<= 1) sum += __shfl_xor(sum, off);
      invl[i][r] = 1.0f / sum;
    }
  __syncthreads();
  // P (normalized) -> LDS in A-operand-friendly layout
#pragma unroll
  for (int i = 0; i < 4; ++i)
#pragma unroll
    for (int kt = 0; kt < 8; ++kt)
#pragma unroll
      for (int r = 0; r < 4; ++r)
        P[(i * 16 + quad * 4 + r) * 136 + kt * 16 + m16] =
            (bf16)(s[i][kt][r] * invl[i][r]);
  __syncthreads();

  // O = P @ V
  f32x4 o[4][4];
#pragma unroll
  for (int i = 0; i < 4; ++i)
#pragma unroll
    for (int j = 0; j < 4; ++j) o[i][j] = zero4();
#pragma unroll
  for (int ks = 0; ks < 4; ++ks) {
    bf16x8 ap[4], bv[4];
#pragma unroll
    for (int i = 0; i < 4; ++i)
      ap[i] = *(const bf16x8*)&P[(i * 16 + m16) * 136 + ks * 32 + quad * 8];
#pragma unroll
    for (int j = 0; j < 4; ++j)
      bv[j] = *(const bf16x8*)&Vt[(j * 16 + m16) * 136 + ks * 32 + quad * 8];
#pragma unroll
    for (int i = 0; i < 4; ++i)
#pragma unroll
      for (int j = 0; j < 4; ++j) o[i][j] = MFMA_BF16(ap[i], bv[j], o[i][j]);
  }
  __syncthreads();
#pragma unroll
  for (int i = 0; i < 4; ++i)
#pragma unroll
    for (int j = 0; j < 4; ++j)
#pragma unroll
      for (int r = 0; r < 4; ++r)
        Ost[(i * 16 + quad * 4 + r) * 64 + j * 16 + m16] = (bf16)o[i][j][r];
  __syncthreads();
  {
    const int r = lane >> 3;
    const int cc = (lane & 7) * 8;
#pragma unroll
    for (int j = 0; j < 8; ++j) {
      const int rr = j * 8 + r;
      storeOut8(Out, tbase + (size_t)rr * DD + cc, &Ost[rr * 64 + cc], f);
    }
  }
}

// ---------------------------------------------------------------------------
// Static attention, flash split-K: one wave per (b, h, split of 320 keys).
// ---------------------------------------------------------------------------
__global__ __launch_bounds__(64) void static_attn(
    const bf16* __restrict__ Q2, const bf16* __restrict__ K2,
    const bf16* __restrict__ V2, const void* __restrict__ tmask,
    const void* __restrict__ smask, float* __restrict__ Opart,
    float* __restrict__ Mpart, float* __restrict__ Lpart,
    const int* __restrict__ dflag) {
  __shared__ __align__(16) char smem[34816];
  bf16* Qs = (bf16*)smem;            // [64][64]
  bf16* Ks = (bf16*)(smem + 8192);   // [64][64]
  bf16* Vt = (bf16*)(smem + 16384);  // [64][72]
  bf16* P = (bf16*)(smem + 25600);   // [64][72]

  const int f = *dflag;
  const int bid = blockIdx.x;
  const int sp = bid % NSPLIT;
  const int bh = bid / NSPLIT;
  const int h = bh & 15;
  const int b = bh >> 4;
  const int lane = threadIdx.x;
  const int quad = lane >> 4;
  const int m16 = lane & 15;

  {
    const int r = lane >> 3, cc = (lane & 7) * 8;
#pragma unroll
    for (int j = 0; j < 8; ++j) {
      const int rr = j * 8 + r;
      *(bf16x8*)&Qs[rr * 64 + cc] =
          *(const bf16x8*)&Q2[((size_t)(b * 64 + rr)) * DD + h * 64 + cc];
    }
  }

  const float scale = 0.125f;
  float m_run[4][4], l_run[4][4];
  f32x4 o[4][4];
#pragma unroll
  for (int i = 0; i < 4; ++i)
#pragma unroll
    for (int r = 0; r < 4; ++r) {
      m_run[i][r] = -1e30f;
      l_run[i][r] = 0.0f;
    }
#pragma unroll
  for (int i = 0; i < 4; ++i)
#pragma unroll
    for (int j = 0; j < 4; ++j) o[i][j] = zero4();

  const int k0 = sp * KCHUNK;
  for (int t = 0; t < 5; ++t) {
    const int kt0 = k0 + t * 64;
    __syncthreads();
    {
      const int r = lane >> 3, cc = (lane & 7) * 8;
#pragma unroll
      for (int j = 0; j < 8; ++j) {
        const int rr = j * 8 + r;
        *(bf16x8*)&Ks[rr * 64 + cc] =
            *(const bf16x8*)&K2[((size_t)b * LL + kt0 + rr) * DD + h * 64 + cc];
      }
    }
#pragma unroll
    for (int kb = 0; kb < 8; ++kb) {
      bf16x8 tmp;
#pragma unroll
      for (int j = 0; j < 8; ++j)
        tmp[j] = V2[((size_t)b * LL + kt0 + kb * 8 + j) * DD + h * 64 + lane];
      *(bf16x8*)&Vt[lane * 72 + kb * 8] = tmp;
    }
    __syncthreads();

    f32x4 s[4][4];
#pragma unroll
    for (int i = 0; i < 4; ++i)
#pragma unroll
      for (int nt = 0; nt < 4; ++nt) s[i][nt] = zero4();
#pragma unroll
    for (int ks = 0; ks < 2; ++ks) {
      bf16x8 aq[4];
#pragma unroll
      for (int i = 0; i < 4; ++i)
        aq[i] = *(const bf16x8*)&Qs[(i * 16 + m16) * 64 + ks * 32 + quad * 8];
#pragma unroll
      for (int nt = 0; nt < 4; ++nt) {
        const bf16x8 bk = *(const bf16x8*)&Ks[(nt * 16 + m16) * 64 + ks * 32 + quad * 8];
#pragma unroll
        for (int i = 0; i < 4; ++i) s[i][nt] = MFMA_BF16(aq[i], bk, s[i][nt]);
      }
    }
    float bias_nt[4];
#pragma unroll
    for (int nt = 0; nt < 4; ++nt) {
      const int kg = kt0 + nt * 16 + m16;
      float mv;
      if (kg < NTT)
        mv = loadS(tmask, (size_t)b * NTT + kg, f);
      else
        mv = loadS(smask, b * 64 + (kg - NTT), f);
      bias_nt[nt] = (mv > 0.5f) ? 0.0f : -1e30f;
    }
#pragma unroll
    for (int i = 0; i < 4; ++i)
#pragma unroll
      for (int r = 0; r < 4; ++r) {
        float mx = -1e30f;
#pragma unroll
        for (int nt = 0; nt < 4; ++nt) {
          float v = s[i][nt][r] * scale + bias_nt[nt];
          s[i][nt][r] = v;
          mx = fmaxf(mx, v);
        }
#pragma unroll
        for (int off = 1; off < 16; off <<= 1) mx = fmaxf(mx, __shfl_xor(mx, off));
        const float m_new = fmaxf(m_run[i][r], mx);
        const float alpha = __expf(m_run[i][r] - m_new);
        float sum = 0.0f;
#pragma unroll
        for (int nt = 0; nt < 4; ++nt) {
          float p = __expf(s[i][nt][r] - m_new);
          s[i][nt][r] = p;
          sum += p;
        }
#pragma unroll
        for (int off = 1; off < 16; off <<= 1) sum += __shfl_xor(sum, off);
        l_run[i][r] = l_run[i][r] * alpha + sum;
        m_run[i][r] = m_new;
#pragma unroll
        for (int j = 0; j < 4; ++j) o[i][j][r] *= alpha;
      }
#pragma unroll
    for (int i = 0; i < 4; ++i)
#pragma unroll
      for (int nt = 0; nt < 4; ++nt)
#pragma unroll
        for (int r = 0; r < 4; ++r)
          P[(i * 16 + quad * 4 + r) * 72 + nt * 16 + m16] = (bf16)s[i][nt][r];
    __syncthreads();
#pragma unroll
    for (int ks = 0; ks < 2; ++ks) {
      bf16x8 ap[4], bv[4];
#pragma unroll
      for (int i = 0; i < 4; ++i)
        ap[i] = *(const bf16x8*)&P[(i * 16 + m16) * 72 + ks * 32 + quad * 8];
#pragma unroll
      for (int j = 0; j < 4; ++j)
        bv[j] = *(const bf16x8*)&Vt[(j * 16 + m16) * 72 + ks * 32 + quad * 8];
#pragma unroll
      for (int i = 0; i < 4; ++i)
#pragma unroll
        for (int j = 0; j < 4; ++j) o[i][j] = MFMA_BF16(ap[i], bv[j], o[i][j]);
    }
  }

  const size_t obase = ((size_t)bh * NSPLIT + sp) * 4096;
#pragma unroll
  for (int i = 0; i < 4; ++i)
#pragma unroll
    for (int j = 0; j < 4; ++j)
#pragma unroll
      for (int r = 0; r < 4; ++r)
        Opart[obase + (size_t)(i * 16 + quad * 4 + r) * 64 + j * 16 + m16] =
            o[i][j][r];
  if (m16 == 0) {
    const size_t mbase = ((size_t)bh * NSPLIT + sp) * 64;
#pragma unroll
    for (int i = 0; i < 4; ++i)
#pragma unroll
      for (int r = 0; r < 4; ++r) {
        Mpart[mbase + i * 16 + quad * 4 + r] = m_run[i][r];
        Lpart[mbase + i * 16 + quad * 4 + r] = l_run[i][r];
      }
  }
}

__global__ __launch_bounds__(64) void static_merge(
    const float* __restrict__ Opart, const float* __restrict__ Mpart,
    const float* __restrict__ Lpart, bf16* __restrict__ Sout) {
  const int bh = blockIdx.x;
  const int b = bh >> 4, h = bh & 15;
  const int lane = threadIdx.x;
  for (int r = 0; r < 64; ++r) {
    float M = -1e30f;
    float ms[NSPLIT];
#pragma unroll
    for (int s = 0; s < NSPLIT; ++s) {
      ms[s] = Mpart[((size_t)bh * NSPLIT + s) * 64 + r];
      M = fmaxf(M, ms[s]);
    }
    float L = 0.0f;
    float acc = 0.0f;
#pragma unroll
    for (int s = 0; s < NSPLIT; ++s) {
      const float w = __expf(ms[s] - M);
      L += Lpart[((size_t)bh * NSPLIT + s) * 64 + r] * w;
      acc += w * Opart[(((size_t)bh * NSPLIT + s) * 64 + r) * 64 + lane];
    }
    Sout[((size_t)(b * 64 + r)) * DD + h * 64 + lane] = (bf16)(acc / L);
  }
}

__global__ __launch_bounds__(256) void gather_qs(const bf16* __restrict__ Q,
                                                 bf16* __restrict__ Q2in) {
  const int t = blockIdx.x * 256 + threadIdx.x;  // 65536 total
  const int row = t >> 7;
  const int cc = (t & 127) * 8;
  const int b = row >> 6, i = row & 63;
  *(bf16x8*)&Q2in[(size_t)row * DD + cc] =
      *(const bf16x8*)&Q[((size_t)b * LL + NTT + i) * DD + cc];
}

__global__ __launch_bounds__(256) void scatter_out(const bf16* __restrict__ S,
                                                   void* __restrict__ Out,
                                                   const int* __restrict__ dflag) {
  const int f = *dflag;
  const int t = blockIdx.x * 256 + threadIdx.x;
  const int row = t >> 7;
  const int cc = (t & 127) * 8;
  const int b = row >> 6, i = row & 63;
  storeOut8(Out, ((size_t)b * LL + NTT + i) * DD + cc, &S[(size_t)row * DD + cc], f);
}

extern "C" void kernel_launch(void* const* d_in, const int* in_sizes, int n_in,
                              void* d_out, int out_size, void* d_ws,
                              size_t ws_size, hipStream_t stream) {
  // Size-driven input identification (dtype-independent: sizes are element
  // counts). q,k,v = the 34078720s in order; Wq,Wk,Wv,out_w = the 1048576s;
  // bq,bk,bv,out_b = the 1024s; masks 32768/512; in_proj 3145728/3072.
  const void* qkv[3] = {nullptr, nullptr, nullptr};
  const void* W4[4] = {nullptr, nullptr, nullptr, nullptr};
  const void* b4[4] = {nullptr, nullptr, nullptr, nullptr};
  const void *tmask = nullptr, *smask = nullptr, *ipw = nullptr, *ipb = nullptr;
  int nbig = 0, nw = 0, nb_ = 0;
  for (int i = 0; i < n_in; ++i) {
    switch (in_sizes[i]) {
      case 34078720: if (nbig < 3) qkv[nbig++] = d_in[i]; break;
      case 32768: tmask = d_in[i]; break;
      case 512: smask = d_in[i]; break;
      case 1048576: if (nw < 4) W4[nw++] = d_in[i]; break;
      case 1024: if (nb_ < 4) b4[nb_++] = d_in[i]; break;
      case 3145728: ipw = d_in[i]; break;
      case 3072: ipb = d_in[i]; break;
      default: break;
    }
  }

  char* w = (char*)d_ws;
  int* dflag = (int*)w; w += 256;
  const size_t BIG = (size_t)NTOK * DD * 2;  // 68,157,440 B
  bf16* Qb = (bf16*)w;  w += BIG;
  bf16* Kb = (bf16*)w;  w += BIG;
  bf16* Vb = (bf16*)w;  w += BIG;
  bf16* Q2in = (bf16*)w;  w += (size_t)512 * DD * 2;
  bf16* Q2 = (bf16*)w;    w += (size_t)512 * DD * 2;
  bf16* SoutB = (bf16*)w; w += (size_t)512 * DD * 2;
  bf16* SoutF = (bf16*)w; w += (size_t)512 * DD * 2;
  float* Opart = (float*)w; w += (size_t)128 * NSPLIT * 4096 * 4;
  float* Mpart = (float*)w; w += (size_t)128 * NSPLIT * 64 * 4;
  float* Lpart = (float*)w; w += (size_t)128 * NSPLIT * 64 * 4;

  // 0: decide external dtype on-device (deterministic; graph-safe)
  detect_dtype<<<1, 256, 0, stream>>>((const unsigned short*)qkv[0], dflag);
  // 1-3: QKV projections (A external -> flex)
  gemm_bt<<<260 * 8, 256, 0, stream>>>(qkv[0], 0, W4[0], 0, b4[0], 0, Qb,
                                       NTOK, DD, DD, 8, dflag, 1);
  gemm_bt<<<260 * 8, 256, 0, stream>>>(qkv[1], 0, W4[1], 0, b4[1], 0, Kb,
                                       NTOK, DD, DD, 8, dflag, 1);
  gemm_bt<<<260 * 8, 256, 0, stream>>>(qkv[2], 0, W4[2], 0, b4[2], 0, Vb,
                                       NTOK, DD, DD, 8, dflag, 1);
  // 4: gather static Q rows before Qb is reused
  gather_qs<<<256, 256, 0, stream>>>(Qb, Q2in);
  // 5: temporal attention -> Out rows [b*4160, b*4160+4096)
  temporal_attn<<<BB * 64 * HH, 64, 0, stream>>>(Qb, Kb, Vb, tmask, smask,
                                                 d_out, dflag);
  // 6-7: second projections (k2 into Qb, v2 into Kb)
  gemm_bt<<<260 * 8, 256, 0, stream>>>(Kb, 0, ipw, (size_t)DD * DD, ipb, DD,
                                       Qb, NTOK, DD, DD, 8, dflag, 0);
  gemm_bt<<<260 * 8, 256, 0, stream>>>(Vb, 0, ipw, (size_t)2 * DD * DD, ipb,
                                       2 * DD, Kb, NTOK, DD, DD, 8, dflag, 0);
  // 8: q2 projection (M=512)
  gemm_bt<<<4 * 8, 256, 0, stream>>>(Q2in, 0, ipw, 0, ipb, 0, Q2, 512, DD, DD,
                                     8, dflag, 0);
  // 9-10: static attention (split-K flash) + merge
  static_attn<<<128 * NSPLIT, 64, 0, stream>>>(Q2, Qb, Kb, tmask, smask,
                                               Opart, Mpart, Lpart, dflag);
  static_merge<<<128, 64, 0, stream>>>(Opart, Mpart, Lpart, SoutB);
  // 11-12: output projection + scatter into Out static rows
  gemm_bt<<<4 * 8, 256, 0, stream>>>(SoutB, 0, W4[3], 0, b4[3], 0, SoutF, 512,
                                     DD, DD, 8, dflag, 0);
  scatter_out<<<256, 256, 0, stream>>>(SoutF, d_out, dflag);
}